// Round 4
// baseline (581.462 us; speedup 1.0000x reference)
//
#include <hip/hip_runtime.h>
#include <hip/hip_bf16.h>
#include <math.h>

// Problem: B=32, L=2048, E=512, Q=512, K=E+Q=1024, M=B*L=65536
// out = [applied (32*512 f32), weights (32*2048 f32)]
//
// v5 design (this round):
//  - R3 post-mortem: scores was LDS-BW-bound (192 KB LDS traffic per CU-step
//    = 1750-2260 cyc of the 3409-cyc step). Fix: eliminate LDS entirely.
//  - scores: ZERO-LDS, ZERO-BARRIER k-loop. B (W, 1 MB bf16, L2-resident)
//    loaded global->VGPR per fragment; A loaded global->VGPR (f32, 128-B
//    row segments, L1/L2 absorbs the 2x wave-pair reuse) and packed to bf16
//    in-register. Manual even/odd register pipeline (static indexing) keeps
//    ~12 loads in flight under pack+MFMA work. No syncthreads until the
//    epilogue reduce.
//  - convert_w: plain bf16 row-major (no swizzle needed anymore).
//  - stats/apply unchanged from R3 (partials -> softmax stats -> stream).

typedef __attribute__((ext_vector_type(8))) short bf16x8;
typedef __attribute__((ext_vector_type(4))) float f32x4;

#define BDIM 32
#define LDIM 2048
#define EDIM 512
#define QDIM 512
#define KDIM 1024
#define MDIM (BDIM * LDIM)

#define BM 128
#define BN 128
#define NCHUNK 32          // K in chunks of 32 bf16 (one 16x16x32 MFMA K-depth)

// pack two fp32 -> two bf16 (round-half-up == RNE except exact ties; ties have
// prob ~2^-16 on random data). 2 v_add + 1 v_perm per 2 elements.
__device__ __forceinline__ unsigned int pack2bf(float lo, float hi) {
    unsigned int a = __builtin_bit_cast(unsigned int, lo) + 0x8000u;
    unsigned int b = __builtin_bit_cast(unsigned int, hi) + 0x8000u;
    return __builtin_amdgcn_perm(b, a, 0x07060302);
}

__device__ __forceinline__ bf16x8 pack_frag(const float4& lo, const float4& hi) {
    union { unsigned int u[4]; bf16x8 v; } r;
    r.u[0] = pack2bf(lo.x, lo.y);
    r.u[1] = pack2bf(lo.z, lo.w);
    r.u[2] = pack2bf(hi.x, hi.y);
    r.u[3] = pack2bf(hi.z, hi.w);
    return r.v;
}

// ---------------------------------------------------------------------------
// W (512x1024 f32 row-major) -> bf16 row-major. 256 blocks x 256 thr,
// 8 elements (16 B out) per thread.
__global__ __launch_bounds__(256) void convert_w_kernel(
    const float* __restrict__ W, unsigned short* __restrict__ Wbf)
{
    const int gid = blockIdx.x * 256 + threadIdx.x;   // 65536 * 8 elems
    const float* src = W + (size_t)gid * 8;
    const float4 a = *(const float4*)(src);
    const float4 c = *(const float4*)(src + 4);
    uint4 o;
    o.x = pack2bf(a.x, a.y); o.y = pack2bf(a.z, a.w);
    o.z = pack2bf(c.x, c.y); o.w = pack2bf(c.z, c.w);
    *(uint4*)(Wbf + (size_t)gid * 8) = o;
}

// ---------------------------------------------------------------------------
// Direct-from-global fragment loads for one K-chunk (32 bf16 columns).
// A: lane reads A[m0+wm+i*16+ln][koff + quad*8 .. +8] as f32 (32 B,
//    16 rows x 128 B contiguous segments per frag instruction).
// B: lane reads Wbf[n0+wn+j*16+ln][c*32 + quad*8 .. +8] (16 B, L2-hot).
__device__ __forceinline__ void load_chunk(
    const float* __restrict__ emb, const float* __restrict__ query,
    const unsigned short* __restrict__ Wbf,
    int arow0, int brow0, int ln, int quad, int c,
    float4 (&a0)[4], float4 (&a1)[4], bf16x8 (&bfr)[4])
{
    const int kq = c * 32 + quad * 8;                 // never straddles Q/E split
    const float* asrc = (kq < QDIM) ? query : emb;
    const int koff = (kq < QDIM) ? kq : (kq - QDIM);
    #pragma unroll
    for (int i = 0; i < 4; i++) {
        const float* p = asrc + (size_t)(arow0 + i * 16) * 512 + koff;
        a0[i] = *(const float4*)p;
        a1[i] = *(const float4*)(p + 4);
    }
    #pragma unroll
    for (int j = 0; j < 4; j++)
        bfr[j] = *(const bf16x8*)(Wbf + (size_t)(brow0 + j * 16) * 1024 + c * 32 + quad * 8);
}

__device__ __forceinline__ void compute_chunk(
    const float4 (&a0)[4], const float4 (&a1)[4], const bf16x8 (&bfr)[4],
    f32x4 (&acc)[4][4])
{
    bf16x8 af[4];
    #pragma unroll
    for (int i = 0; i < 4; i++) af[i] = pack_frag(a0[i], a1[i]);
    #pragma unroll
    for (int i = 0; i < 4; i++)
        #pragma unroll
        for (int j = 0; j < 4; j++)
            acc[i][j] = __builtin_amdgcn_mfma_f32_16x16x32_bf16(af[i], bfr[j], acc[i][j], 0, 0, 0);
}

__global__ __launch_bounds__(256) void scores_kernel(
    const float* __restrict__ emb, const float* __restrict__ query,
    const unsigned short* __restrict__ Wbf, const float* __restrict__ b_attn,
    const float* __restrict__ v_w, float* __restrict__ part)
{
    __shared__ float redbuf[256];     // epilogue only

    const int tid = threadIdx.x;
    const int bid = blockIdx.x;
    // XCD-aware: the 4 ntile-sharers of one mtile are consecutive slots on
    // the same XCD -> A rows hit the same 4MB L2.
    const int xcd = bid & 7;
    const int slot = bid >> 3;
    const int mtile = xcd * 64 + (slot >> 2);
    const int ntile = slot & 3;
    const int m0 = mtile * BM;
    const int n0 = ntile * BN;

    const int lane = tid & 63;
    const int wv = tid >> 6;
    const int wm = (wv >> 1) * 64;    // wave's 64x64 quadrant
    const int wn = (wv & 1) * 64;
    const int quad = lane >> 4;
    const int ln = lane & 15;

    const int arow0 = m0 + wm + ln;
    const int brow0 = n0 + wn + ln;

    f32x4 acc[4][4];
    #pragma unroll
    for (int i = 0; i < 4; i++)
        #pragma unroll
        for (int j = 0; j < 4; j++)
            acc[i][j] = (f32x4){0.f, 0.f, 0.f, 0.f};

    // even/odd register pipeline, 1 chunk deep (static indexing only)
    float4 a0A[4], a1A[4], a0B[4], a1B[4];
    bf16x8 bA[4], bB[4];

    load_chunk(emb, query, Wbf, arow0, brow0, ln, quad, 0, a0A, a1A, bA);

    #pragma unroll 1
    for (int c = 0; c < NCHUNK; c += 2) {
        load_chunk(emb, query, Wbf, arow0, brow0, ln, quad, c + 1, a0B, a1B, bB);
        compute_chunk(a0A, a1A, bA, acc);
        if (c + 2 < NCHUNK)
            load_chunk(emb, query, Wbf, arow0, brow0, ln, quad, c + 2, a0A, a1A, bA);
        compute_chunk(a0B, a1B, bB, acc);
    }

    // ---- fused epilogue: sum_n tanh(x + b[n]) * v_w[n] ----
    // Per-wave 16-lane shfl reduce, LDS cross-wave (wn-half) reduce, then one
    // plain store per (ntile, m) into the partials buffer.
    float bj[4], vj[4];
    #pragma unroll
    for (int j = 0; j < 4; j++) {
        const int n = n0 + wn + j * 16 + ln;
        bj[j] = b_attn[n];
        vj[j] = v_w[n];
    }
    const int half = wn >> 6;
    #pragma unroll
    for (int i = 0; i < 4; i++) {
        #pragma unroll
        for (int r = 0; r < 4; r++) {
            float s = 0.f;
            #pragma unroll
            for (int j = 0; j < 4; j++)
                s += tanhf(acc[i][j][r] + bj[j]) * vj[j];
            #pragma unroll
            for (int off = 1; off < 16; off <<= 1)
                s += __shfl_xor(s, off, 64);
            if (ln == 0)
                redbuf[half * 128 + wm + i * 16 + quad * 4 + r] = s;
        }
    }
    __syncthreads();
    if (tid < 128)
        part[(size_t)ntile * MDIM + m0 + tid] = redbuf[tid] + redbuf[128 + tid];
}

// ---------------------------------------------------------------------------
// Softmax stats once per batch row; sums the 4 ntile partials inline.
// Grid: 32 blocks x 256 thr.
__global__ __launch_bounds__(256) void softmax_stats_kernel(
    const float* __restrict__ part, float* __restrict__ out_weights)
{
    const int b = blockIdx.x;
    const int tid = threadIdx.x;
    __shared__ float red[4];

    float sv[8];
    #pragma unroll
    for (int t = 0; t < 8; t++) {
        const size_t idx = (size_t)b * LDIM + tid + t * 256;
        float s = part[idx];
        #pragma unroll
        for (int j = 1; j < 4; j++) s += part[(size_t)j * MDIM + idx];
        sv[t] = s;
    }

    float mx = sv[0];
    #pragma unroll
    for (int t = 1; t < 8; t++) mx = fmaxf(mx, sv[t]);
    #pragma unroll
    for (int off = 1; off < 64; off <<= 1) mx = fmaxf(mx, __shfl_xor(mx, off, 64));
    if ((tid & 63) == 0) red[tid >> 6] = mx;
    __syncthreads();
    mx = fmaxf(fmaxf(red[0], red[1]), fmaxf(red[2], red[3]));

    float sm = 0.f;
    #pragma unroll
    for (int t = 0; t < 8; t++) sm += expf(sv[t] - mx);
    #pragma unroll
    for (int off = 1; off < 64; off <<= 1) sm += __shfl_xor(sm, off, 64);
    __syncthreads();
    if ((tid & 63) == 0) red[tid >> 6] = sm;
    __syncthreads();
    sm = red[0] + red[1] + red[2] + red[3];
    const float inv = 1.f / sm;

    #pragma unroll
    for (int t = 0; t < 8; t++)
        out_weights[(size_t)b * LDIM + tid + t * 256] = expf(sv[t] - mx) * inv;
}

// Pure-stream weighted sum: w read directly from out_weights.
// Grid: 32 b x 64 chunks (32 rows) = 2048 blocks x 256 thr.
__global__ __launch_bounds__(256) void apply_kernel(
    const float* __restrict__ emb, const float* __restrict__ w,
    float* __restrict__ out_applied)
{
    const int b = blockIdx.x >> 6;
    const int chunk = blockIdx.x & 63;
    const int l0 = chunk * 32;
    const int tid = threadIdx.x;

    __shared__ float wls[32];
    __shared__ float partial[512];

    if (tid < 32) wls[tid] = w[(size_t)b * LDIM + l0 + tid];
    __syncthreads();

    const int half = tid >> 7;          // wave-uniform
    const int cg = tid & 127;           // column group of 4 floats
    float4 acc = {0.f, 0.f, 0.f, 0.f};
    const float* ebase = emb + ((size_t)b * LDIM + l0 + half) * EDIM + cg * 4;
    #pragma unroll
    for (int i = 0; i < 16; i++) {
        const float4 v = *(const float4*)(ebase + (size_t)2 * i * EDIM);
        const float ww = wls[half + 2 * i];
        acc.x += ww * v.x;
        acc.y += ww * v.y;
        acc.z += ww * v.z;
        acc.w += ww * v.w;
    }
    if (half == 1) *(float4*)&partial[cg * 4] = acc;
    __syncthreads();
    if (half == 0) {
        const float4 p = *(const float4*)&partial[cg * 4];
        float* dst = out_applied + (size_t)b * EDIM + cg * 4;
        atomicAdd(dst + 0, acc.x + p.x);
        atomicAdd(dst + 1, acc.y + p.y);
        atomicAdd(dst + 2, acc.z + p.z);
        atomicAdd(dst + 3, acc.w + p.w);
    }
}

extern "C" void kernel_launch(void* const* d_in, const int* in_sizes, int n_in,
                              void* d_out, int out_size, void* d_ws, size_t ws_size,
                              hipStream_t stream) {
    const float* emb    = (const float*)d_in[0];
    const float* query  = (const float*)d_in[1];
    const float* W      = (const float*)d_in[2];
    const float* b_attn = (const float*)d_in[3];
    const float* v_w    = (const float*)d_in[4];

    float* out     = (float*)d_out;
    float* applied = out;                 // 32*512 floats
    float* weights = out + BDIM * EDIM;   // 32*2048 floats

    float* part = (float*)d_ws;                                              // 4*MDIM f32 = 1 MB
    unsigned short* Wbf = (unsigned short*)((char*)d_ws + (size_t)4 * MDIM * 4); // 1 MB bf16 W

    hipMemsetAsync(applied, 0, (size_t)BDIM * EDIM * sizeof(float), stream);

    convert_w_kernel<<<256, 256, 0, stream>>>(W, Wbf);

    // grid = (M/BM) * (N/BN) = 512 * 4 = 2048 blocks
    scores_kernel<<<2048, 256, 0, stream>>>(emb, query, Wbf, b_attn, v_w, part);

    softmax_stats_kernel<<<32, 256, 0, stream>>>(part, weights);

    // grid = B * 64 chunks = 2048 blocks
    apply_kernel<<<2048, 256, 0, stream>>>(emb, weights, applied);
}

// Round 5
// 385.433 us; speedup vs baseline: 1.5086x; 1.5086x over previous
//
#include <hip/hip_runtime.h>
#include <hip/hip_bf16.h>
#include <math.h>

// Problem: B=32, L=2048, E=512, Q=512, K=E+Q=1024, M=B*L=65536
// out = [applied (32*512 f32), weights (32*2048 f32)]
//
// v6 design (this round):
//  - Diagnosis: R1 structure is latency-bound at 2 waves/SIMD (8 waves/CU);
//    neither barrier micro-opt (R3 null) nor LDS removal (R4, -2x) helped.
//  - scores: SAME tile (BM=BN=128, BK=64, dbuf LDS, 2 blocks/CU) but 8 waves
//    per block (512 thr, wave grid 2x4, 64x32 output/wave, 32 AGPR acc).
//    -> 16 waves/CU = 4/SIMD, same barrier count, halved per-thread staging.
//    __launch_bounds__(512,4) caps regs at 128 so both blocks stay resident.
//    1-deep A prefetch: loads issued before compute, packed+written after.
//  - apply: back to 64-row chunks / 1024 blocks (R2 config, -28us proven).
//  - convert_w/stats: unchanged from R3.

typedef __attribute__((ext_vector_type(8))) short bf16x8;
typedef __attribute__((ext_vector_type(4))) float f32x4;

#define BDIM 32
#define LDIM 2048
#define EDIM 512
#define QDIM 512
#define KDIM 1024
#define MDIM (BDIM * LDIM)

#define BM 128
#define BN 128
#define BK 64
#define NSTEPS (KDIM / BK)   // 16

// pack two fp32 -> two bf16 (round-half-up == RNE except exact ties; ties have
// prob ~2^-16 on random data). 2 v_add + 1 v_perm per 2 elements.
__device__ __forceinline__ unsigned int pack2bf(float lo, float hi) {
    unsigned int a = __builtin_bit_cast(unsigned int, lo) + 0x8000u;
    unsigned int b = __builtin_bit_cast(unsigned int, hi) + 0x8000u;
    return __builtin_amdgcn_perm(b, a, 0x07060302);
}

// ---------------------------------------------------------------------------
// W (512x1024 f32 row-major) -> bf16 with per-row byte-XOR swizzle baked in
// (Wsw.byte[n][j] = bf16(W)[n].byte[j ^ ((n&7)<<4)]) so the GEMM fills LDS
// linearly with global_load_lds and reads conflict-free (R1-proven pair).
__global__ __launch_bounds__(256) void convert_w_kernel(
    const float* __restrict__ W, unsigned short* __restrict__ Wsw)
{
    const int gid = blockIdx.x * 256 + threadIdx.x;   // 512 rows * 128 16B-units
    const int n  = gid >> 7;
    const int jb = (gid & 127) * 16;                  // output byte offset in 2048B row
    const int sb = jb ^ ((n & 7) << 4);               // source byte offset (16B-granular XOR)
    const float* src = W + (size_t)n * KDIM + (sb >> 1); // bf16-byte off -> float off = sb/2
    const float4 a = *(const float4*)(src);
    const float4 c = *(const float4*)(src + 4);
    uint4 o;
    o.x = pack2bf(a.x, a.y); o.y = pack2bf(a.z, a.w);
    o.z = pack2bf(c.x, c.y); o.w = pack2bf(c.z, c.w);
    *(uint4*)((char*)Wsw + (size_t)n * 2048 + jb) = o;
}

// ---------------------------------------------------------------------------
__device__ __forceinline__ bf16x8 lds_frag(const unsigned short* buf, int row, int cb) {
    return *(const bf16x8*)((const char*)buf + row * 128 + (cb ^ ((row & 7) << 4)));
}

// A staging, 512 threads: 4 passes of 32 rows; thread -> row p*32+(tid>>4),
// float col (tid&15)*4.
__device__ __forceinline__ void load_a(const float* __restrict__ emb,
                                       const float* __restrict__ query,
                                       int m0, int kstep, int arow, int acol,
                                       float4 (&r)[4])
{
    const int k0 = kstep * BK;
    const float* asrc = (k0 < QDIM) ? query : emb;
    const int koff = (k0 < QDIM) ? k0 : (k0 - QDIM);
    #pragma unroll
    for (int p = 0; p < 4; p++)
        r[p] = *(const float4*)(asrc + (size_t)(m0 + p * 32 + arow) * 512 + koff + acol);
}

__device__ __forceinline__ void write_a(unsigned short* buf, int arow, int acolb,
                                        int axor, const float4 (&r)[4])
{
    #pragma unroll
    for (int p = 0; p < 4; p++) {
        uint2 pk;
        pk.x = pack2bf(r[p].x, r[p].y);
        pk.y = pack2bf(r[p].z, r[p].w);
        *(uint2*)((char*)buf + (p * 32 + arow) * 128 + (acolb ^ axor)) = pk;
    }
}

// B fill via global_load_lds, 512 threads x 2 issues of 16B = 16KB tile.
// Issue p: LDS byte p*8192 + tid*16 (wave-uniform base + lane*16);
// global row n0 + p*64 + (tid>>3), byte col kb + (tid&7)*16.
__device__ __forceinline__ void gll_b(const unsigned short* __restrict__ Wsw,
                                      unsigned short* buf, int n0, int kstep,
                                      int brow, int bcb, int wvoff)
{
    const size_t kb = (size_t)kstep * (BK * 2);
    #pragma unroll
    for (int p = 0; p < 2; p++) {
        const char* g = (const char*)Wsw + (size_t)(n0 + p * 64 + brow) * 2048 + kb + bcb;
        __builtin_amdgcn_global_load_lds(
            (const __attribute__((address_space(1))) void*)g,
            (__attribute__((address_space(3))) void*)((char*)buf + p * 8192 + wvoff),
            16, 0, 0);
    }
}

// Wave computes 64x32: i=0..3 (16-row steps), j=0..1 (16-col steps).
__device__ __forceinline__ void compute_step(const unsigned short* a_,
                                             const unsigned short* b_,
                                             int wm, int wn, int ln, int quad,
                                             f32x4 (&acc)[4][2])
{
    __builtin_amdgcn_s_setprio(1);
    #pragma unroll
    for (int ks = 0; ks < 2; ks++) {
        bf16x8 af[4], bfr[2];
        #pragma unroll
        for (int i = 0; i < 4; i++) af[i] = lds_frag(a_, wm + i * 16 + ln, ks * 64 + quad * 16);
        #pragma unroll
        for (int j = 0; j < 2; j++) bfr[j] = lds_frag(b_, wn + j * 16 + ln, ks * 64 + quad * 16);
        #pragma unroll
        for (int i = 0; i < 4; i++)
            #pragma unroll
            for (int j = 0; j < 2; j++)
                acc[i][j] = __builtin_amdgcn_mfma_f32_16x16x32_bf16(af[i], bfr[j], acc[i][j], 0, 0, 0);
    }
    __builtin_amdgcn_s_setprio(0);
}

__global__ __launch_bounds__(512, 4) void scores_kernel(
    const float* __restrict__ emb, const float* __restrict__ query,
    const unsigned short* __restrict__ Wsw, const float* __restrict__ b_attn,
    const float* __restrict__ v_w, float* __restrict__ part)
{
    // dbuf: 4 x 16KB = 64 KB -> 2 blocks/CU (16 waves/CU = 4/SIMD)
    __shared__ __align__(16) unsigned short As[2][BM * BK];
    __shared__ __align__(16) unsigned short Bs[2][BN * BK];

    const int tid = threadIdx.x;
    const int bid = blockIdx.x;
    // XCD-aware: the 4 ntile-sharers of one mtile are consecutive slots on
    // the same XCD -> A rows hit the same 4MB L2.
    const int xcd = bid & 7;
    const int slot = bid >> 3;
    const int mtile = xcd * 64 + (slot >> 2);
    const int ntile = slot & 3;
    const int m0 = mtile * BM;
    const int n0 = ntile * BN;

    const int lane = tid & 63;
    const int wv = tid >> 6;          // 8 waves: 2 (m) x 4 (n)
    const int wm = (wv >> 2) * 64;    // wave's 64x32 output patch
    const int wn = (wv & 3) * 32;
    const int quad = lane >> 4;
    const int ln = lane & 15;

    const int arow  = tid >> 4;       // 0..31
    const int acol  = (tid & 15) * 4;
    const int acolb = acol * 2;
    const int axor  = (arow & 7) << 4;

    const int brow = tid >> 3;        // 0..63
    const int bcb  = (tid & 7) * 16;
    const int wvoff = __builtin_amdgcn_readfirstlane(wv << 10);

    f32x4 acc[4][2];
    #pragma unroll
    for (int i = 0; i < 4; i++)
        #pragma unroll
        for (int j = 0; j < 2; j++)
            acc[i][j] = (f32x4){0.f, 0.f, 0.f, 0.f};

    float4 ra[4];

    // prologue: stage step 0 (exposed latency once)
    gll_b(Wsw, &Bs[0][0], n0, 0, brow, bcb, wvoff);
    load_a(emb, query, m0, 0, arow, acol, ra);
    write_a(&As[0][0], arow, acolb, axor, ra);
    __syncthreads();

    #pragma unroll 1
    for (int t = 0; t < NSTEPS; t += 2) {
        // even: issue t+1 staging early, compute buf0 (= t), then pack/write.
        gll_b(Wsw, &Bs[1][0], n0, t + 1, brow, bcb, wvoff);
        load_a(emb, query, m0, t + 1, arow, acol, ra);
        compute_step(&As[0][0], &Bs[0][0], wm, wn, ln, quad, acc);
        write_a(&As[1][0], arow, acolb, axor, ra);
        __syncthreads();

        // odd: issue t+2 staging early (if any), compute buf1 (= t+1).
        if (t + 2 < NSTEPS) {
            gll_b(Wsw, &Bs[0][0], n0, t + 2, brow, bcb, wvoff);
            load_a(emb, query, m0, t + 2, arow, acol, ra);
        }
        compute_step(&As[1][0], &Bs[1][0], wm, wn, ln, quad, acc);
        if (t + 2 < NSTEPS)
            write_a(&As[0][0], arow, acolb, axor, ra);
        __syncthreads();
    }

    // ---- fused epilogue: sum_n tanh(x + b[n]) * v_w[n] ----
    // Per-wave 16-lane shfl reduce -> redbuf[wv][64], then 4 wn-sharers
    // summed by 128 threads, one plain store per (ntile, m).
    float bj[2], vj[2];
    #pragma unroll
    for (int j = 0; j < 2; j++) {
        const int n = n0 + wn + j * 16 + ln;
        bj[j] = b_attn[n];
        vj[j] = v_w[n];
    }
    float* redbuf = (float*)&As[0][0];   // 8*64 floats = 2KB (LDS reuse)
    #pragma unroll
    for (int i = 0; i < 4; i++) {
        #pragma unroll
        for (int r = 0; r < 4; r++) {
            float s = 0.f;
            #pragma unroll
            for (int j = 0; j < 2; j++)
                s += tanhf(acc[i][j][r] + bj[j]) * vj[j];
            #pragma unroll
            for (int off = 1; off < 16; off <<= 1)
                s += __shfl_xor(s, off, 64);
            if (ln == 0)
                redbuf[wv * 64 + i * 16 + quad * 4 + r] = s;
        }
    }
    __syncthreads();
    if (tid < 128) {
        const int h = tid >> 6;          // row half -> waves h*4 .. h*4+3
        const int r = tid & 63;
        const float s = redbuf[(h * 4 + 0) * 64 + r] + redbuf[(h * 4 + 1) * 64 + r]
                      + redbuf[(h * 4 + 2) * 64 + r] + redbuf[(h * 4 + 3) * 64 + r];
        part[(size_t)ntile * MDIM + m0 + tid] = s;
    }
}

// ---------------------------------------------------------------------------
// Softmax stats once per batch row; sums the 4 ntile partials inline.
// Grid: 32 blocks x 256 thr.
__global__ __launch_bounds__(256) void softmax_stats_kernel(
    const float* __restrict__ part, float* __restrict__ out_weights)
{
    const int b = blockIdx.x;
    const int tid = threadIdx.x;
    __shared__ float red[4];

    float sv[8];
    #pragma unroll
    for (int t = 0; t < 8; t++) {
        const size_t idx = (size_t)b * LDIM + tid + t * 256;
        float s = part[idx];
        #pragma unroll
        for (int j = 1; j < 4; j++) s += part[(size_t)j * MDIM + idx];
        sv[t] = s;
    }

    float mx = sv[0];
    #pragma unroll
    for (int t = 1; t < 8; t++) mx = fmaxf(mx, sv[t]);
    #pragma unroll
    for (int off = 1; off < 64; off <<= 1) mx = fmaxf(mx, __shfl_xor(mx, off, 64));
    if ((tid & 63) == 0) red[tid >> 6] = mx;
    __syncthreads();
    mx = fmaxf(fmaxf(red[0], red[1]), fmaxf(red[2], red[3]));

    float sm = 0.f;
    #pragma unroll
    for (int t = 0; t < 8; t++) sm += expf(sv[t] - mx);
    #pragma unroll
    for (int off = 1; off < 64; off <<= 1) sm += __shfl_xor(sm, off, 64);
    __syncthreads();
    if ((tid & 63) == 0) red[tid >> 6] = sm;
    __syncthreads();
    sm = red[0] + red[1] + red[2] + red[3];
    const float inv = 1.f / sm;

    #pragma unroll
    for (int t = 0; t < 8; t++)
        out_weights[(size_t)b * LDIM + tid + t * 256] = expf(sv[t] - mx) * inv;
}

// Pure-stream weighted sum, 64-row chunks (R2-proven config).
// Grid: 32 b x 32 chunks = 1024 blocks x 256 thr.
__global__ __launch_bounds__(256) void apply_kernel(
    const float* __restrict__ emb, const float* __restrict__ w,
    float* __restrict__ out_applied)
{
    const int b = blockIdx.x >> 5;
    const int chunk = blockIdx.x & 31;
    const int l0 = chunk * 64;
    const int tid = threadIdx.x;

    __shared__ float wls[64];
    __shared__ float partial[512];

    if (tid < 64) wls[tid] = w[(size_t)b * LDIM + l0 + tid];
    __syncthreads();

    const int half = tid >> 7;          // wave-uniform
    const int cg = tid & 127;           // column group of 4 floats
    float4 acc = {0.f, 0.f, 0.f, 0.f};
    const float* ebase = emb + ((size_t)b * LDIM + l0 + half) * EDIM + cg * 4;
    #pragma unroll 8
    for (int i = 0; i < 32; i++) {
        const float4 v = *(const float4*)(ebase + (size_t)2 * i * EDIM);
        const float ww = wls[half + 2 * i];
        acc.x += ww * v.x;
        acc.y += ww * v.y;
        acc.z += ww * v.z;
        acc.w += ww * v.w;
    }
    if (half == 1) *(float4*)&partial[cg * 4] = acc;
    __syncthreads();
    if (half == 0) {
        const float4 p = *(const float4*)&partial[cg * 4];
        float* dst = out_applied + (size_t)b * EDIM + cg * 4;
        atomicAdd(dst + 0, acc.x + p.x);
        atomicAdd(dst + 1, acc.y + p.y);
        atomicAdd(dst + 2, acc.z + p.z);
        atomicAdd(dst + 3, acc.w + p.w);
    }
}

extern "C" void kernel_launch(void* const* d_in, const int* in_sizes, int n_in,
                              void* d_out, int out_size, void* d_ws, size_t ws_size,
                              hipStream_t stream) {
    const float* emb    = (const float*)d_in[0];
    const float* query  = (const float*)d_in[1];
    const float* W      = (const float*)d_in[2];
    const float* b_attn = (const float*)d_in[3];
    const float* v_w    = (const float*)d_in[4];

    float* out     = (float*)d_out;
    float* applied = out;                 // 32*512 floats
    float* weights = out + BDIM * EDIM;   // 32*2048 floats

    float* part = (float*)d_ws;                                              // 4*MDIM f32 = 1 MB
    unsigned short* Wsw = (unsigned short*)((char*)d_ws + (size_t)4 * MDIM * 4); // 1 MB swizzled bf16 W

    hipMemsetAsync(applied, 0, (size_t)BDIM * EDIM * sizeof(float), stream);

    convert_w_kernel<<<256, 256, 0, stream>>>(W, Wsw);

    // grid = (M/BM) * (N/BN) = 512 * 4 = 2048 blocks
    scores_kernel<<<2048, 512, 0, stream>>>(emb, query, Wsw, b_attn, v_w, part);

    softmax_stats_kernel<<<32, 256, 0, stream>>>(part, weights);

    // grid = B * 32 chunks = 1024 blocks
    apply_kernel<<<1024, 256, 0, stream>>>(emb, weights, applied);
}